// Round 10
// baseline (124.458 us; speedup 1.0000x reference)
//
#include <hip/hip_runtime.h>
#include <math.h>

// R8 exact structure (proven 48.2us: rolled j3-loop, W12 [ij][j3][o] layout,
// folded scales, 6-exp smear) x 2 edges per thread. Rationale: R8 is ~40%
// idle on per-wave latency (block-start position loads + 5 weight-stream
// waits in the j3 loop); pairing edges halves per-edge latency exposure.
// Unlike R3 (spilled at VGPR 64): live state ~35 floats/edge, early phase
// sequential per edge, j3-loop rolled; plain __launch_bounds__(256) lets the
// allocator go to ~100 VGPR (R6 precedent: it used 80 without spilling).
// SPILL CHECK: WRITE_SIZE must stay ~47 MB.

#define WS_W12  0     // [20][5][9] *i21*i105          = 900
#define WS_WV   900   // [5][9]     *i21*i105*i3       = 45
#define WS_WS   945   // [20]       *i21*i50           = 20
#define WS_CS   965   // scalar     *i21*i50*i3        = 1
#define WS_SVV  966   // [5][5]     *i10               = 25
#define WS_VSV  991   // [4][5]     *i10               = 20
#define WS_VVV1 1011  // [5]        *i10*i2            = 5
#define WS_VSV2 1016  // [5][5]     *i50               = 25
#define WS_VVV2 1041  // [5]        *i2*i50            = 5
#define WS_VVO2 1046  // [5][9]     *i3*i105           = 45
#define WS_TOT  1091

__global__ __launch_bounds__(256) void fds_precompose(
    const float* __restrict__ W1_sso, const float* __restrict__ W1_svv,
    const float* __restrict__ W1_vsv, const float* __restrict__ W1_vvo,
    const float* __restrict__ W1_vvv, const float* __restrict__ W2_sso,
    const float* __restrict__ W2_svv, const float* __restrict__ W2_vsv,
    const float* __restrict__ W2_vvo, const float* __restrict__ W2_vvv,
    float* __restrict__ ws)
{
    const float I2 = 0.70710678118654752f, I3 = 0.57735026918962576f;
    const float I10 = 0.31622776601683794f, I21 = 0.21821789023599239f;
    const float I105 = 0.09759000729485332f, I50 = 0.14142135623730950f;
    int tid = threadIdx.x;
    for (int idx = tid; idx < 900; idx += 256) {
        int o = idx % 9, j3 = (idx / 9) % 5, ij = idx / 45;
        float acc = 0.f;
        for (int k2 = 0; k2 < 20; k2++)
            acc = fmaf(W1_sso[ij * 20 + k2], W2_sso[(k2 * 5 + j3) * 9 + o], acc);
        ws[WS_W12 + idx] = acc * (I21 * I105);
    }
    for (int idx = tid; idx < 45; idx += 256) {
        int o = idx % 9, j3 = idx / 9;
        float acc = 0.f;
        for (int k2 = 0; k2 < 20; k2++)
            acc = fmaf(W1_vvo[k2], W2_sso[(k2 * 5 + j3) * 9 + o], acc);
        ws[WS_WV + idx] = acc * (I21 * I105 * I3);
    }
    for (int idx = tid; idx < 20; idx += 256) {
        float acc = 0.f;
        for (int k2 = 0; k2 < 20; k2++)
            acc = fmaf(W1_sso[idx * 20 + k2], W2_svv[k2], acc);
        ws[WS_WS + idx] = acc * (I21 * I50);
    }
    if (tid == 0) {
        float acc = 0.f;
        for (int k2 = 0; k2 < 20; k2++) acc = fmaf(W1_vvo[k2], W2_svv[k2], acc);
        ws[WS_CS] = acc * (I21 * I50 * I3);
    }
    for (int idx = tid; idx < 25; idx += 256) ws[WS_SVV + idx] = W1_svv[idx] * I10;
    for (int idx = tid; idx < 20; idx += 256) ws[WS_VSV + idx] = W1_vsv[idx] * I10;
    for (int idx = tid; idx < 5; idx += 256)  ws[WS_VVV1 + idx] = W1_vvv[idx] * (I10 * I2);
    for (int idx = tid; idx < 25; idx += 256) ws[WS_VSV2 + idx] = W2_vsv[idx] * I50;
    for (int idx = tid; idx < 5; idx += 256)  ws[WS_VVV2 + idx] = W2_vvv[idx] * (I2 * I50);
    for (int idx = tid; idx < 45; idx += 256) ws[WS_VVO2 + idx] = W2_vvo[idx] * (I3 * I105);
}

__global__ __launch_bounds__(256) void fds_kernel(
    const float* __restrict__ lig, const float* __restrict__ rec,
    const float* __restrict__ W12, const float* __restrict__ WV,
    const float* __restrict__ WSp, const float* __restrict__ CSp,
    const float* __restrict__ SVV, const float* __restrict__ VSV,
    const float* __restrict__ VVV1, const float* __restrict__ VSV2,
    const float* __restrict__ VVV2, const float* __restrict__ VVO2,
    float* __restrict__ out, int E)
{
    const float C5 = -0.32f;          // -0.5 / 1.25^2
    const float C4 = -0.18f;          // -0.5 / (5/3)^2
    const float EK1  = 0.60653065971263342f;   // e^-0.5
    const float EK4  = 0.13533528323661270f;   // e^-2
    const float EK9  = 0.011108996538242306f;  // e^-4.5
    const float EK16 = 3.3546262790251185e-4f; // e^-8
    const float EM1  = 0.36787944117144233f;   // e^-1

    int t = blockIdx.x * blockDim.x + threadIdx.x;
    int P = E >> 1;
    if (t >= P) return;

    // issue ALL position loads up front (edges 2t and 2t+1: 6 float4 each arr)
    const float4* lp = (const float4*)lig + 6 * (size_t)t;
    const float4* rp = (const float4*)rec + 6 * (size_t)t;
    float4 L[6], R[6];
#pragma unroll
    for (int q = 0; q < 6; q++) { L[q] = lp[q]; R[q] = rp[q]; }

    // persistent per-edge state after the early phase (~35 floats/edge)
    float p12s[2][20], accs[2][9], av[2][3], dot12v[2], s3c[2], uu[2];

#pragma unroll
    for (int u = 0; u < 2; u++) {
        float4 l0 = L[3*u], l1 = L[3*u+1], l2 = L[3*u+2];
        float4 r0 = R[3*u], r1 = R[3*u+1], r2 = R[3*u+2];

        float e1x = l0.w - r0.w, e1y = l1.x - r1.x, e1z = l1.y - r1.y;
        float e2x = l1.z - r1.z, e2y = l1.w - r1.w, e2z = l2.x - r2.x;
        float e3x = l2.y - r2.y, e3y = l2.z - r2.z, e3z = l2.w - r2.w;

        float q1 = fmaf(e1x, e1x, fmaf(e1y, e1y, e1z * e1z)) + 1e-12f;
        float q2 = fmaf(e2x, e2x, fmaf(e2y, e2y, e2z * e2z)) + 1e-12f;
        float q3 = fmaf(e3x, e3x, fmaf(e3y, e3y, e3z * e3z)) + 1e-12f;
        float ri1 = rsqrtf(q1), ri2 = rsqrtf(q2), ri3 = rsqrtf(q3);
        float d1 = q1 * ri1, d2 = q2 * ri2, d3 = q3 * ri3;
        float v1x = e1x * ri1, v1y = e1y * ri1, v1z = e1z * ri1;
        float v2x = e2x * ri2, v2y = e2y * ri2, v2z = e2z * ri2;
        float v3x = e3x * ri3, v3y = e3y * ri3, v3z = e3z * ri3;

        // smear: s[i] = E0 * r^i * K[i^2]
        float s1[5], s3[5], s2[4], r3;
        {
            float E0 = __expf(C5 * d1 * d1), r = __expf(0.8f * d1);
            float rr = r * r, uq = E0 * r, v = E0 * rr;
            s1[0] = E0; s1[1] = uq * EK1; s1[2] = v * EK4;
            s1[3] = v * r * EK9; s1[4] = v * rr * EK16;
        }
        {
            float E0 = __expf(C5 * d3 * d3); r3 = __expf(0.8f * d3);
            float rr = r3 * r3, uq = E0 * r3, v = E0 * rr;
            s3[0] = E0; s3[1] = uq * EK1; s3[2] = v * EK4;
            s3[3] = v * r3 * EK9; s3[4] = v * rr * EK16;
        }
        {
            float E0 = __expf(C4 * d2 * d2), r = __expf(0.6f * d2);
            float rr = r * r;
            s2[0] = E0; s2[1] = E0 * r * EK1; s2[2] = E0 * rr * EK4;
            s2[3] = E0 * rr * r * EK9;
        }

        float dot12 = fmaf(v1x, v2x, fmaf(v1y, v2y, v1z * v2z));  // raw
        float cr12x = v1y * v2z - v1z * v2y;                       // raw
        float cr12y = v1z * v2x - v1x * v2z;
        float cr12z = v1x * v2y - v1y * v2x;

        float A[5], B[5];
#pragma unroll
        for (int k = 0; k < 5; k++) {
            float a = 0.f, b = 0.f;
#pragma unroll
            for (int i = 0; i < 5; i++) a = fmaf(s1[i], SVV[i * 5 + k], a);
#pragma unroll
            for (int j = 0; j < 4; j++) b = fmaf(s2[j], VSV[j * 5 + k], b);
            A[k] = a; B[k] = b;
        }
        float ov[5][3];
#pragma unroll
        for (int k = 0; k < 5; k++) {
            float w = VVV1[k];
            ov[k][0] = fmaf(A[k], v2x, fmaf(B[k], v1x, cr12x * w));
            ov[k][1] = fmaf(A[k], v2y, fmaf(B[k], v1y, cr12y * w));
            ov[k][2] = fmaf(A[k], v2z, fmaf(B[k], v1z, cr12z * w));
        }

        float dot2[5];
#pragma unroll
        for (int k = 0; k < 5; k++)
            dot2[k] = fmaf(ov[k][0], v3x, fmaf(ov[k][1], v3y, ov[k][2] * v3z));

#pragma unroll
        for (int o = 0; o < 9; o++) accs[u][o] = 0.f;
#pragma unroll
        for (int k = 0; k < 5; k++)
#pragma unroll
            for (int o = 0; o < 9; o++)
                accs[u][o] = fmaf(dot2[k], VVO2[k * 9 + o], accs[u][o]);

        float a0 = 0.f, a1 = 0.f, a2 = 0.f;
#pragma unroll
        for (int k = 0; k < 5; k++) {
            float c = 0.f;
#pragma unroll
            for (int j = 0; j < 5; j++) c = fmaf(s3[j], VSV2[k * 5 + j], c);
            float w = VVV2[k];
            float cx = ov[k][1] * v3z - ov[k][2] * v3y;
            float cy = ov[k][2] * v3x - ov[k][0] * v3z;
            float cz = ov[k][0] * v3y - ov[k][1] * v3x;
            a0 = fmaf(ov[k][0], c, fmaf(cx, w, a0));
            a1 = fmaf(ov[k][1], c, fmaf(cy, w, a1));
            a2 = fmaf(ov[k][2], c, fmaf(cz, w, a2));
        }
        // ov dead

#pragma unroll
        for (int i = 0; i < 5; i++)
#pragma unroll
            for (int j = 0; j < 4; j++) p12s[u][i * 4 + j] = s1[i] * s2[j];

        float S = dot12 * CSp[0];
#pragma unroll
        for (int ij = 0; ij < 20; ij++) S = fmaf(p12s[u][ij], WSp[ij], S);
        av[u][0] = fmaf(S, v3x, a0);
        av[u][1] = fmaf(S, v3y, a1);
        av[u][2] = fmaf(S, v3z, a2);

        dot12v[u] = dot12;
        s3c[u] = s3[0];
        uu[u] = r3 * EK1;
    }

    // ---- shared j3-loop (NOT unrolled): one weight stream feeds BOTH edges.
    {
        const float* wj = W12;
        const float* wv = WV;
        float sA = s3c[0], sB = s3c[1];
        float uA = uu[0],  uB = uu[1];
#pragma clang loop unroll(disable)
        for (int j3 = 0; j3 < 5; ++j3) {
            float fv0 = dot12v[0] * sA;
            float fv1 = dot12v[1] * sB;
#pragma unroll
            for (int o = 0; o < 9; o++) {
                float w = wv[o];
                accs[0][o] = fmaf(fv0, w, accs[0][o]);
                accs[1][o] = fmaf(fv1, w, accs[1][o]);
            }
#pragma unroll
            for (int ij = 0; ij < 20; ij++) {
                float f0 = p12s[0][ij] * sA;
                float f1 = p12s[1][ij] * sB;
#pragma unroll
                for (int o = 0; o < 9; o++) {
                    float w = wj[ij * 45 + o];
                    accs[0][o] = fmaf(f0, w, accs[0][o]);
                    accs[1][o] = fmaf(f1, w, accs[1][o]);
                }
            }
            sA *= uA; uA *= EM1;
            sB *= uB; uB *= EM1;
            wj += 9; wv += 9;
        }
    }

    // ---- packed float2 stores: per segment, edges 2t,2t+1 are 6 consecutive
    float res0[12], res1[12];
#pragma unroll
    for (int o = 0; o < 9; o++) { res0[o] = accs[0][o]; res1[o] = accs[1][o]; }
#pragma unroll
    for (int c = 0; c < 3; c++) { res0[9 + c] = av[0][c]; res1[9 + c] = av[1][c]; }

    size_t E3 = (size_t)E * 3;
#pragma unroll
    for (int s = 0; s < 4; s++) {
        float2* dst = (float2*)(out + (size_t)s * E3 + 6 * (size_t)t);
        dst[0] = make_float2(res0[3 * s + 0], res0[3 * s + 1]);
        dst[1] = make_float2(res0[3 * s + 2], res1[3 * s + 0]);
        dst[2] = make_float2(res1[3 * s + 1], res1[3 * s + 2]);
    }
}

extern "C" void kernel_launch(void* const* d_in, const int* in_sizes, int n_in,
                              void* d_out, int out_size, void* d_ws, size_t ws_size,
                              hipStream_t stream) {
    const float* lig    = (const float*)d_in[0];
    const float* rec    = (const float*)d_in[1];
    const float* W1_sso = (const float*)d_in[2];
    const float* W1_svv = (const float*)d_in[3];
    const float* W1_vsv = (const float*)d_in[4];
    const float* W1_vvo = (const float*)d_in[5];
    const float* W1_vvv = (const float*)d_in[6];
    const float* W2_sso = (const float*)d_in[7];
    const float* W2_svv = (const float*)d_in[8];
    const float* W2_vsv = (const float*)d_in[9];
    const float* W2_vvo = (const float*)d_in[10];
    const float* W2_vvv = (const float*)d_in[11];
    float* ws = (float*)d_ws;

    fds_precompose<<<1, 256, 0, stream>>>(W1_sso, W1_svv, W1_vsv, W1_vvo, W1_vvv,
                                          W2_sso, W2_svv, W2_vsv, W2_vvo, W2_vvv, ws);

    int E = in_sizes[0] / 12;  // N*3 / 12 = N/4
    int P = E >> 1;            // E even (N = 4M)
    int blocks = (P + 255) / 256;
    fds_kernel<<<blocks, 256, 0, stream>>>(
        lig, rec,
        ws + WS_W12, ws + WS_WV, ws + WS_WS, ws + WS_CS,
        ws + WS_SVV, ws + WS_VSV, ws + WS_VVV1, ws + WS_VSV2,
        ws + WS_VVV2, ws + WS_VVO2,
        (float*)d_out, E);
}

// Round 11
// 47.372 us; speedup vs baseline: 2.6272x; 2.6272x over previous
//
#include <hip/hip_runtime.h>
#include <math.h>

// R8 skeleton (proven 48.2us) + f16-dot2 offload of the big contraction:
// v_dot2_f32_f16 (__builtin_amdgcn_fdot2) does 2 f16 MACs/instr with FP32
// accumulate. W12 precomposed as f16x2 pairs over adjacent ij (W12H[j3][q][o],
// q=ij/2, 90 dwords/j3-iter); p12 kept ONLY as f16x2 packs (10 dwords, built
// by packed f16 muls from s1/s2); S-reduction also dot2-ified. WV + all
// small contractions stay f32. Geometry/smear/vector path identical to R8.

typedef _Float16 h2 __attribute__((ext_vector_type(2)));

#define WS_W12H 0     // [5][10][9] f16x2 packs (uint dwords)    = 450
#define WS_WV   450   // [5][9] f32 *i21*i105*i3                 = 45
#define WS_WSH  495   // [10] f16x2 packs of WS pairs            = 10
#define WS_CS   505   // scalar f32                              = 1
#define WS_SVV  506   // [5][5] f32 *i10                         = 25
#define WS_VSV  531   // [4][5] f32 *i10                         = 20
#define WS_VVV1 551   // [5]    f32 *i10*i2                      = 5
#define WS_VSV2 556   // [5][5] f32 *i50                         = 25
#define WS_VVV2 581   // [5]    f32 *i2*i50                      = 5
#define WS_VVO2 586   // [5][9] f32 *i3*i105                     = 45
#define WS_TOT  631

__global__ __launch_bounds__(256) void fds_precompose(
    const float* __restrict__ W1_sso, const float* __restrict__ W1_svv,
    const float* __restrict__ W1_vsv, const float* __restrict__ W1_vvo,
    const float* __restrict__ W1_vvv, const float* __restrict__ W2_sso,
    const float* __restrict__ W2_svv, const float* __restrict__ W2_vsv,
    const float* __restrict__ W2_vvo, const float* __restrict__ W2_vvv,
    float* __restrict__ ws)
{
    const float I2 = 0.70710678118654752f, I3 = 0.57735026918962576f;
    const float I10 = 0.31622776601683794f, I21 = 0.21821789023599239f;
    const float I105 = 0.09759000729485332f, I50 = 0.14142135623730950f;
    int tid = threadIdx.x;
    // W12H[j3][q][o] = pack(f16(W12[2q,j3,o]), f16(W12[2q+1,j3,o]))
    for (int idx = tid; idx < 450; idx += 256) {
        int o = idx % 9, q = (idx / 9) % 10, j3 = idx / 90;
        float a0 = 0.f, a1 = 0.f;
        for (int k2 = 0; k2 < 20; k2++) {
            float w2 = W2_sso[(k2 * 5 + j3) * 9 + o];
            a0 = fmaf(W1_sso[(2 * q) * 20 + k2], w2, a0);
            a1 = fmaf(W1_sso[(2 * q + 1) * 20 + k2], w2, a1);
        }
        h2 p = { (_Float16)(a0 * (I21 * I105)), (_Float16)(a1 * (I21 * I105)) };
        ws[WS_W12H + idx] = __builtin_bit_cast(float, p);
    }
    for (int idx = tid; idx < 45; idx += 256) {
        int o = idx % 9, j3 = idx / 9;
        float acc = 0.f;
        for (int k2 = 0; k2 < 20; k2++)
            acc = fmaf(W1_vvo[k2], W2_sso[(k2 * 5 + j3) * 9 + o], acc);
        ws[WS_WV + idx] = acc * (I21 * I105 * I3);
    }
    // WSH[q] = pack(f16(WS[2q]), f16(WS[2q+1]))
    for (int idx = tid; idx < 10; idx += 256) {
        float a0 = 0.f, a1 = 0.f;
        for (int k2 = 0; k2 < 20; k2++) {
            a0 = fmaf(W1_sso[(2 * idx) * 20 + k2], W2_svv[k2], a0);
            a1 = fmaf(W1_sso[(2 * idx + 1) * 20 + k2], W2_svv[k2], a1);
        }
        h2 p = { (_Float16)(a0 * (I21 * I50)), (_Float16)(a1 * (I21 * I50)) };
        ws[WS_WSH + idx] = __builtin_bit_cast(float, p);
    }
    if (tid == 0) {
        float acc = 0.f;
        for (int k2 = 0; k2 < 20; k2++) acc = fmaf(W1_vvo[k2], W2_svv[k2], acc);
        ws[WS_CS] = acc * (I21 * I50 * I3);
    }
    for (int idx = tid; idx < 25; idx += 256) ws[WS_SVV + idx] = W1_svv[idx] * I10;
    for (int idx = tid; idx < 20; idx += 256) ws[WS_VSV + idx] = W1_vsv[idx] * I10;
    for (int idx = tid; idx < 5; idx += 256)  ws[WS_VVV1 + idx] = W1_vvv[idx] * (I10 * I2);
    for (int idx = tid; idx < 25; idx += 256) ws[WS_VSV2 + idx] = W2_vsv[idx] * I50;
    for (int idx = tid; idx < 5; idx += 256)  ws[WS_VVV2 + idx] = W2_vvv[idx] * (I2 * I50);
    for (int idx = tid; idx < 45; idx += 256) ws[WS_VVO2 + idx] = W2_vvo[idx] * (I3 * I105);
}

__global__ __launch_bounds__(256) void fds_kernel(
    const float* __restrict__ lig, const float* __restrict__ rec,
    const float* __restrict__ W12Hf, const float* __restrict__ WV,
    const float* __restrict__ WSHf, const float* __restrict__ CSp,
    const float* __restrict__ SVV, const float* __restrict__ VSV,
    const float* __restrict__ VVV1, const float* __restrict__ VSV2,
    const float* __restrict__ VVV2, const float* __restrict__ VVO2,
    float* __restrict__ out, int E)
{
    const float C5 = -0.32f;          // -0.5 / 1.25^2
    const float C4 = -0.18f;          // -0.5 / (5/3)^2
    const float EK1  = 0.60653065971263342f;   // e^-0.5
    const float EK4  = 0.13533528323661270f;   // e^-2
    const float EK9  = 0.011108996538242306f;  // e^-4.5
    const float EK16 = 3.3546262790251185e-4f; // e^-8
    const float EM1  = 0.36787944117144233f;   // e^-1

    const h2* __restrict__ W12H = (const h2*)W12Hf;
    const h2* __restrict__ WSH  = (const h2*)WSHf;

    int e = blockIdx.x * blockDim.x + threadIdx.x;
    if (e >= E) return;

    const float4* lp = (const float4*)lig + 3 * (size_t)e;
    const float4* rp = (const float4*)rec + 3 * (size_t)e;
    float4 l0 = lp[0], l1 = lp[1], l2 = lp[2];
    float4 r0 = rp[0], r1 = rp[1], r2 = rp[2];

    // row 4e+1 = floats 3..5, row 4e+2 = floats 6..8, row 4e+3 = floats 9..11
    float e1x = l0.w - r0.w, e1y = l1.x - r1.x, e1z = l1.y - r1.y;
    float e2x = l1.z - r1.z, e2y = l1.w - r1.w, e2z = l2.x - r2.x;
    float e3x = l2.y - r2.y, e3y = l2.z - r2.z, e3z = l2.w - r2.w;

    float q1 = fmaf(e1x, e1x, fmaf(e1y, e1y, e1z * e1z)) + 1e-12f;
    float q2 = fmaf(e2x, e2x, fmaf(e2y, e2y, e2z * e2z)) + 1e-12f;
    float q3 = fmaf(e3x, e3x, fmaf(e3y, e3y, e3z * e3z)) + 1e-12f;
    float ri1 = rsqrtf(q1), ri2 = rsqrtf(q2), ri3 = rsqrtf(q3);
    float d1 = q1 * ri1, d2 = q2 * ri2, d3 = q3 * ri3;
    float v1x = e1x * ri1, v1y = e1y * ri1, v1z = e1z * ri1;
    float v2x = e2x * ri2, v2y = e2y * ri2, v2z = e2z * ri2;
    float v3x = e3x * ri3, v3y = e3y * ri3, v3z = e3z * ri3;

    // smear: s[i] = exp(C*(d - h*i)^2) = E0 * r^i * K[i^2]
    float s1[5], s3[5], s2[4];
    float r3;
    {
        float E0 = __expf(C5 * d1 * d1), r = __expf(0.8f * d1);
        float rr = r * r, u = E0 * r, v = E0 * rr;
        s1[0] = E0; s1[1] = u * EK1; s1[2] = v * EK4;
        s1[3] = v * r * EK9; s1[4] = v * rr * EK16;
    }
    {
        float E0 = __expf(C5 * d3 * d3); r3 = __expf(0.8f * d3);
        float rr = r3 * r3, u = E0 * r3, v = E0 * rr;
        s3[0] = E0; s3[1] = u * EK1; s3[2] = v * EK4;
        s3[3] = v * r3 * EK9; s3[4] = v * rr * EK16;
    }
    {
        float E0 = __expf(C4 * d2 * d2), r = __expf(0.6f * d2);
        float rr = r * r;
        s2[0] = E0; s2[1] = E0 * r * EK1; s2[2] = E0 * rr * EK4;
        s2[3] = E0 * rr * r * EK9;
    }

    float dot12 = fmaf(v1x, v2x, fmaf(v1y, v2y, v1z * v2z));  // raw
    float cr12x = v1y * v2z - v1z * v2y;                       // raw
    float cr12y = v1z * v2x - v1x * v2z;
    float cr12z = v1x * v2y - v1y * v2x;

    // layer 1 vector path (scales folded into SVV/VSV/VVV1)
    float A[5], B[5];
#pragma unroll
    for (int k = 0; k < 5; k++) {
        float a = 0.f, b = 0.f;
#pragma unroll
        for (int i = 0; i < 5; i++) a = fmaf(s1[i], SVV[i * 5 + k], a);
#pragma unroll
        for (int j = 0; j < 4; j++) b = fmaf(s2[j], VSV[j * 5 + k], b);
        A[k] = a; B[k] = b;
    }
    float ov[5][3];
#pragma unroll
    for (int k = 0; k < 5; k++) {
        float w = VVV1[k];
        ov[k][0] = fmaf(A[k], v2x, fmaf(B[k], v1x, cr12x * w));
        ov[k][1] = fmaf(A[k], v2y, fmaf(B[k], v1y, cr12y * w));
        ov[k][2] = fmaf(A[k], v2z, fmaf(B[k], v1z, cr12z * w));
    }

    float dot2[5];
#pragma unroll
    for (int k = 0; k < 5; k++)
        dot2[k] = fmaf(ov[k][0], v3x, fmaf(ov[k][1], v3y, ov[k][2] * v3z)); // raw

    float accs[9];
#pragma unroll
    for (int o = 0; o < 9; o++) accs[o] = 0.f;
#pragma unroll
    for (int k = 0; k < 5; k++)
#pragma unroll
        for (int o = 0; o < 9; o++) accs[o] = fmaf(dot2[k], VVO2[k * 9 + o], accs[o]);

    float av0 = 0.f, av1 = 0.f, av2 = 0.f;
#pragma unroll
    for (int k = 0; k < 5; k++) {
        float c = 0.f;
#pragma unroll
        for (int j = 0; j < 5; j++) c = fmaf(s3[j], VSV2[k * 5 + j], c);
        float w = VVV2[k];
        float cx = ov[k][1] * v3z - ov[k][2] * v3y;  // raw cross
        float cy = ov[k][2] * v3x - ov[k][0] * v3z;
        float cz = ov[k][0] * v3y - ov[k][1] * v3x;
        av0 = fmaf(ov[k][0], c, fmaf(cx, w, av0));
        av1 = fmaf(ov[k][1], c, fmaf(cy, w, av1));
        av2 = fmaf(ov[k][2], c, fmaf(cz, w, av2));
    }
    // ov dead from here

    // ---- p12 as f16x2 packs only: p12h[i*2+m] = {s1[i],s1[i]} * {s2[2m],s2[2m+1]}
    h2 p12h[10];
    {
        h2 s2h[2];
        s2h[0] = (h2){ (_Float16)s2[0], (_Float16)s2[1] };
        s2h[1] = (h2){ (_Float16)s2[2], (_Float16)s2[3] };
#pragma unroll
        for (int i = 0; i < 5; i++) {
            _Float16 s1h = (_Float16)s1[i];
            h2 s1b = (h2){ s1h, s1h };
            p12h[i * 2 + 0] = s1b * s2h[0];
            p12h[i * 2 + 1] = s1b * s2h[1];
        }
    }

    // S = p12 . WS + dot12 * cS  (dot2-ified)
    float S = dot12 * CSp[0];
#pragma unroll
    for (int q = 0; q < 10; q++)
        S = __builtin_amdgcn_fdot2(p12h[q], WSH[q], S, false);
    av0 = fmaf(S, v3x, av0);
    av1 = fmaf(S, v3y, av1);
    av2 = fmaf(S, v3z, av2);

    // ---- j3-loop (NOT unrolled): 10 pk_mul + 90 fdot2 + 9 f32 FMA per iter
    {
        const h2* wj = W12H;
        const float* wv = WV;
        float s3c = s3[0];
        float uu = r3 * EK1;
#pragma clang loop unroll(disable)
        for (int j3 = 0; j3 < 5; ++j3) {
            float fv = dot12 * s3c;
#pragma unroll
            for (int o = 0; o < 9; o++) accs[o] = fmaf(fv, wv[o], accs[o]);
            _Float16 sh = (_Float16)s3c;
            h2 shb = (h2){ sh, sh };
#pragma unroll
            for (int q = 0; q < 10; q++) {
                h2 f = p12h[q] * shb;
#pragma unroll
                for (int o = 0; o < 9; o++)
                    accs[o] = __builtin_amdgcn_fdot2(f, wj[q * 9 + o], accs[o], false);
            }
            s3c *= uu; uu *= EM1;
            wj += 90; wv += 9;
        }
    }

    size_t E3 = (size_t)E * 3;
    size_t b = (size_t)e * 3;
    out[b + 0]          = accs[0];   // s_rot
    out[b + 1]          = accs[1];
    out[b + 2]          = accs[2];
    out[E3 + b + 0]     = accs[3];   // s_tr
    out[E3 + b + 1]     = accs[4];
    out[E3 + b + 2]     = accs[5];
    out[2 * E3 + b + 0] = accs[6];   // t_rot
    out[2 * E3 + b + 1] = accs[7];
    out[2 * E3 + b + 2] = accs[8];
    out[3 * E3 + b + 0] = av0;       // t_tr
    out[3 * E3 + b + 1] = av1;
    out[3 * E3 + b + 2] = av2;
}

extern "C" void kernel_launch(void* const* d_in, const int* in_sizes, int n_in,
                              void* d_out, int out_size, void* d_ws, size_t ws_size,
                              hipStream_t stream) {
    const float* lig    = (const float*)d_in[0];
    const float* rec    = (const float*)d_in[1];
    const float* W1_sso = (const float*)d_in[2];
    const float* W1_svv = (const float*)d_in[3];
    const float* W1_vsv = (const float*)d_in[4];
    const float* W1_vvo = (const float*)d_in[5];
    const float* W1_vvv = (const float*)d_in[6];
    const float* W2_sso = (const float*)d_in[7];
    const float* W2_svv = (const float*)d_in[8];
    const float* W2_vsv = (const float*)d_in[9];
    const float* W2_vvo = (const float*)d_in[10];
    const float* W2_vvv = (const float*)d_in[11];
    float* ws = (float*)d_ws;

    fds_precompose<<<1, 256, 0, stream>>>(W1_sso, W1_svv, W1_vsv, W1_vvo, W1_vvv,
                                          W2_sso, W2_svv, W2_vsv, W2_vvo, W2_vvv, ws);

    int E = in_sizes[0] / 12;  // N*3 / 12 = N/4
    int blocks = (E + 255) / 256;
    fds_kernel<<<blocks, 256, 0, stream>>>(
        lig, rec,
        ws + WS_W12H, ws + WS_WV, ws + WS_WSH, ws + WS_CS,
        ws + WS_SVV, ws + WS_VSV, ws + WS_VVV1, ws + WS_VSV2,
        ws + WS_VVV2, ws + WS_VVO2,
        (float*)d_out, E);
}

// Round 13
// 45.272 us; speedup vs baseline: 2.7491x; 1.0464x over previous
//
#include <hip/hip_runtime.h>
#include <math.h>

// R11 EXACT memory layout + rolled j3-loop (passed post-timing at 44.6us),
// with ONE change: the independent f32 vector path (A/B/ov/dot2/VVO2/av)
// moved AFTER the j3 weight-stream loop, so its ~300 independent ops can
// overlap the loop's final lgkm waits / drain phase. R12's full unroll +
// merged layout (post-timing validation failure, mechanism unidentified)
// is fully reverted.

typedef _Float16 h2 __attribute__((ext_vector_type(2)));

#define WS_W12H 0     // [5][10][9] f16x2 packs (uint dwords)    = 450
#define WS_WV   450   // [5][9] f32 *i21*i105*i3                 = 45
#define WS_WSH  495   // [10] f16x2 packs of WS pairs            = 10
#define WS_CS   505   // scalar f32                              = 1
#define WS_SVV  506   // [5][5] f32 *i10                         = 25
#define WS_VSV  531   // [4][5] f32 *i10                         = 20
#define WS_VVV1 551   // [5]    f32 *i10*i2                      = 5
#define WS_VSV2 556   // [5][5] f32 *i50                         = 25
#define WS_VVV2 581   // [5]    f32 *i2*i50                      = 5
#define WS_VVO2 586   // [5][9] f32 *i3*i105                     = 45
#define WS_TOT  631

__global__ __launch_bounds__(256) void fds_precompose(
    const float* __restrict__ W1_sso, const float* __restrict__ W1_svv,
    const float* __restrict__ W1_vsv, const float* __restrict__ W1_vvo,
    const float* __restrict__ W1_vvv, const float* __restrict__ W2_sso,
    const float* __restrict__ W2_svv, const float* __restrict__ W2_vsv,
    const float* __restrict__ W2_vvo, const float* __restrict__ W2_vvv,
    float* __restrict__ ws)
{
    const float I2 = 0.70710678118654752f, I3 = 0.57735026918962576f;
    const float I10 = 0.31622776601683794f, I21 = 0.21821789023599239f;
    const float I105 = 0.09759000729485332f, I50 = 0.14142135623730950f;
    int tid = threadIdx.x;
    // W12H[j3][q][o] = pack(f16(W12[2q,j3,o]), f16(W12[2q+1,j3,o]))
    for (int idx = tid; idx < 450; idx += 256) {
        int o = idx % 9, q = (idx / 9) % 10, j3 = idx / 90;
        float a0 = 0.f, a1 = 0.f;
        for (int k2 = 0; k2 < 20; k2++) {
            float w2 = W2_sso[(k2 * 5 + j3) * 9 + o];
            a0 = fmaf(W1_sso[(2 * q) * 20 + k2], w2, a0);
            a1 = fmaf(W1_sso[(2 * q + 1) * 20 + k2], w2, a1);
        }
        h2 p = { (_Float16)(a0 * (I21 * I105)), (_Float16)(a1 * (I21 * I105)) };
        ws[WS_W12H + idx] = __builtin_bit_cast(float, p);
    }
    for (int idx = tid; idx < 45; idx += 256) {
        int o = idx % 9, j3 = idx / 9;
        float acc = 0.f;
        for (int k2 = 0; k2 < 20; k2++)
            acc = fmaf(W1_vvo[k2], W2_sso[(k2 * 5 + j3) * 9 + o], acc);
        ws[WS_WV + idx] = acc * (I21 * I105 * I3);
    }
    // WSH[q] = pack(f16(WS[2q]), f16(WS[2q+1]))
    for (int idx = tid; idx < 10; idx += 256) {
        float a0 = 0.f, a1 = 0.f;
        for (int k2 = 0; k2 < 20; k2++) {
            a0 = fmaf(W1_sso[(2 * idx) * 20 + k2], W2_svv[k2], a0);
            a1 = fmaf(W1_sso[(2 * idx + 1) * 20 + k2], W2_svv[k2], a1);
        }
        h2 p = { (_Float16)(a0 * (I21 * I50)), (_Float16)(a1 * (I21 * I50)) };
        ws[WS_WSH + idx] = __builtin_bit_cast(float, p);
    }
    if (tid == 0) {
        float acc = 0.f;
        for (int k2 = 0; k2 < 20; k2++) acc = fmaf(W1_vvo[k2], W2_svv[k2], acc);
        ws[WS_CS] = acc * (I21 * I50 * I3);
    }
    for (int idx = tid; idx < 25; idx += 256) ws[WS_SVV + idx] = W1_svv[idx] * I10;
    for (int idx = tid; idx < 20; idx += 256) ws[WS_VSV + idx] = W1_vsv[idx] * I10;
    for (int idx = tid; idx < 5; idx += 256)  ws[WS_VVV1 + idx] = W1_vvv[idx] * (I10 * I2);
    for (int idx = tid; idx < 25; idx += 256) ws[WS_VSV2 + idx] = W2_vsv[idx] * I50;
    for (int idx = tid; idx < 5; idx += 256)  ws[WS_VVV2 + idx] = W2_vvv[idx] * (I2 * I50);
    for (int idx = tid; idx < 45; idx += 256) ws[WS_VVO2 + idx] = W2_vvo[idx] * (I3 * I105);
}

__global__ __launch_bounds__(256) void fds_kernel(
    const float* __restrict__ lig, const float* __restrict__ rec,
    const float* __restrict__ W12Hf, const float* __restrict__ WV,
    const float* __restrict__ WSHf, const float* __restrict__ CSp,
    const float* __restrict__ SVV, const float* __restrict__ VSV,
    const float* __restrict__ VVV1, const float* __restrict__ VSV2,
    const float* __restrict__ VVV2, const float* __restrict__ VVO2,
    float* __restrict__ out, int E)
{
    const float C5 = -0.32f;          // -0.5 / 1.25^2
    const float C4 = -0.18f;          // -0.5 / (5/3)^2
    const float EK1  = 0.60653065971263342f;   // e^-0.5
    const float EK4  = 0.13533528323661270f;   // e^-2
    const float EK9  = 0.011108996538242306f;  // e^-4.5
    const float EK16 = 3.3546262790251185e-4f; // e^-8
    const float EM1  = 0.36787944117144233f;   // e^-1

    const h2* __restrict__ W12H = (const h2*)W12Hf;
    const h2* __restrict__ WSH  = (const h2*)WSHf;

    int e = blockIdx.x * blockDim.x + threadIdx.x;
    if (e >= E) return;

    const float4* lp = (const float4*)lig + 3 * (size_t)e;
    const float4* rp = (const float4*)rec + 3 * (size_t)e;
    float4 l0 = lp[0], l1 = lp[1], l2 = lp[2];
    float4 r0 = rp[0], r1 = rp[1], r2 = rp[2];

    // row 4e+1 = floats 3..5, row 4e+2 = floats 6..8, row 4e+3 = floats 9..11
    float e1x = l0.w - r0.w, e1y = l1.x - r1.x, e1z = l1.y - r1.y;
    float e2x = l1.z - r1.z, e2y = l1.w - r1.w, e2z = l2.x - r2.x;
    float e3x = l2.y - r2.y, e3y = l2.z - r2.z, e3z = l2.w - r2.w;

    float q1 = fmaf(e1x, e1x, fmaf(e1y, e1y, e1z * e1z)) + 1e-12f;
    float q2 = fmaf(e2x, e2x, fmaf(e2y, e2y, e2z * e2z)) + 1e-12f;
    float q3 = fmaf(e3x, e3x, fmaf(e3y, e3y, e3z * e3z)) + 1e-12f;
    float ri1 = rsqrtf(q1), ri2 = rsqrtf(q2), ri3 = rsqrtf(q3);
    float d1 = q1 * ri1, d2 = q2 * ri2, d3 = q3 * ri3;
    float v1x = e1x * ri1, v1y = e1y * ri1, v1z = e1z * ri1;
    float v2x = e2x * ri2, v2y = e2y * ri2, v2z = e2z * ri2;
    float v3x = e3x * ri3, v3y = e3y * ri3, v3z = e3z * ri3;

    // smear: s[i] = exp(C*(d - h*i)^2) = E0 * r^i * K[i^2]
    float s1[5], s3[5], s2[4];
    float r3;
    {
        float E0 = __expf(C5 * d1 * d1), r = __expf(0.8f * d1);
        float rr = r * r, u = E0 * r, v = E0 * rr;
        s1[0] = E0; s1[1] = u * EK1; s1[2] = v * EK4;
        s1[3] = v * r * EK9; s1[4] = v * rr * EK16;
    }
    {
        float E0 = __expf(C5 * d3 * d3); r3 = __expf(0.8f * d3);
        float rr = r3 * r3, u = E0 * r3, v = E0 * rr;
        s3[0] = E0; s3[1] = u * EK1; s3[2] = v * EK4;
        s3[3] = v * r3 * EK9; s3[4] = v * rr * EK16;
    }
    {
        float E0 = __expf(C4 * d2 * d2), r = __expf(0.6f * d2);
        float rr = r * r;
        s2[0] = E0; s2[1] = E0 * r * EK1; s2[2] = E0 * rr * EK4;
        s2[3] = E0 * rr * r * EK9;
    }

    float dot12 = fmaf(v1x, v2x, fmaf(v1y, v2y, v1z * v2z));  // raw
    float cr12x = v1y * v2z - v1z * v2y;                       // raw
    float cr12y = v1z * v2x - v1x * v2z;
    float cr12z = v1x * v2y - v1y * v2x;

    // ---- p12 as f16x2 packs only
    h2 p12h[10];
    {
        h2 s2h0 = (h2){ (_Float16)s2[0], (_Float16)s2[1] };
        h2 s2h1 = (h2){ (_Float16)s2[2], (_Float16)s2[3] };
#pragma unroll
        for (int i = 0; i < 5; i++) {
            _Float16 s1h = (_Float16)s1[i];
            h2 s1b = (h2){ s1h, s1h };
            p12h[i * 2 + 0] = s1b * s2h0;
            p12h[i * 2 + 1] = s1b * s2h1;
        }
    }

    // S = p12 . WS + dot12 * cS  (dot2-ified)
    float S = dot12 * CSp[0];
#pragma unroll
    for (int q = 0; q < 10; q++)
        S = __builtin_amdgcn_fdot2(p12h[q], WSH[q], S, false);

    // ---- j3-loop (NOT unrolled): 10 pk_mul + 90 fdot2 + 9 f32 FMA per iter
    float accs[9];
#pragma unroll
    for (int o = 0; o < 9; o++) accs[o] = 0.f;
    {
        const h2* wj = W12H;
        const float* wv = WV;
        float s3c = s3[0];
        float uu = r3 * EK1;
#pragma clang loop unroll(disable)
        for (int j3 = 0; j3 < 5; ++j3) {
            float fv = dot12 * s3c;
#pragma unroll
            for (int o = 0; o < 9; o++) accs[o] = fmaf(fv, wv[o], accs[o]);
            _Float16 sh = (_Float16)s3c;
            h2 shb = (h2){ sh, sh };
#pragma unroll
            for (int q = 0; q < 10; q++) {
                h2 f = p12h[q] * shb;
#pragma unroll
                for (int o = 0; o < 9; o++)
                    accs[o] = __builtin_amdgcn_fdot2(f, wj[q * 9 + o], accs[o], false);
            }
            s3c *= uu; uu *= EM1;
            wj += 90; wv += 9;
        }
    }

    // ---- vector path AFTER the big contraction (R13's single change vs R11):
    // ~300 independent f32 ops that can overlap the j3-loop's final waits.
    float A[5], B[5];
#pragma unroll
    for (int k = 0; k < 5; k++) {
        float a = 0.f, b = 0.f;
#pragma unroll
        for (int i = 0; i < 5; i++) a = fmaf(s1[i], SVV[i * 5 + k], a);
#pragma unroll
        for (int j = 0; j < 4; j++) b = fmaf(s2[j], VSV[j * 5 + k], b);
        A[k] = a; B[k] = b;
    }
    float ov[5][3];
#pragma unroll
    for (int k = 0; k < 5; k++) {
        float w = VVV1[k];
        ov[k][0] = fmaf(A[k], v2x, fmaf(B[k], v1x, cr12x * w));
        ov[k][1] = fmaf(A[k], v2y, fmaf(B[k], v1y, cr12y * w));
        ov[k][2] = fmaf(A[k], v2z, fmaf(B[k], v1z, cr12z * w));
    }

    float dot2[5];
#pragma unroll
    for (int k = 0; k < 5; k++)
        dot2[k] = fmaf(ov[k][0], v3x, fmaf(ov[k][1], v3y, ov[k][2] * v3z)); // raw

#pragma unroll
    for (int k = 0; k < 5; k++)
#pragma unroll
        for (int o = 0; o < 9; o++) accs[o] = fmaf(dot2[k], VVO2[k * 9 + o], accs[o]);

    float av0 = 0.f, av1 = 0.f, av2 = 0.f;
#pragma unroll
    for (int k = 0; k < 5; k++) {
        float c = 0.f;
#pragma unroll
        for (int j = 0; j < 5; j++) c = fmaf(s3[j], VSV2[k * 5 + j], c);
        float w = VVV2[k];
        float cx = ov[k][1] * v3z - ov[k][2] * v3y;  // raw cross
        float cy = ov[k][2] * v3x - ov[k][0] * v3z;
        float cz = ov[k][0] * v3y - ov[k][1] * v3x;
        av0 = fmaf(ov[k][0], c, fmaf(cx, w, av0));
        av1 = fmaf(ov[k][1], c, fmaf(cy, w, av1));
        av2 = fmaf(ov[k][2], c, fmaf(cz, w, av2));
    }
    av0 = fmaf(S, v3x, av0);
    av1 = fmaf(S, v3y, av1);
    av2 = fmaf(S, v3z, av2);

    size_t E3 = (size_t)E * 3;
    size_t b = (size_t)e * 3;
    out[b + 0]          = accs[0];   // s_rot
    out[b + 1]          = accs[1];
    out[b + 2]          = accs[2];
    out[E3 + b + 0]     = accs[3];   // s_tr
    out[E3 + b + 1]     = accs[4];
    out[E3 + b + 2]     = accs[5];
    out[2 * E3 + b + 0] = accs[6];   // t_rot
    out[2 * E3 + b + 1] = accs[7];
    out[2 * E3 + b + 2] = accs[8];
    out[3 * E3 + b + 0] = av0;       // t_tr
    out[3 * E3 + b + 1] = av1;
    out[3 * E3 + b + 2] = av2;
}

extern "C" void kernel_launch(void* const* d_in, const int* in_sizes, int n_in,
                              void* d_out, int out_size, void* d_ws, size_t ws_size,
                              hipStream_t stream) {
    const float* lig    = (const float*)d_in[0];
    const float* rec    = (const float*)d_in[1];
    const float* W1_sso = (const float*)d_in[2];
    const float* W1_svv = (const float*)d_in[3];
    const float* W1_vsv = (const float*)d_in[4];
    const float* W1_vvo = (const float*)d_in[5];
    const float* W1_vvv = (const float*)d_in[6];
    const float* W2_sso = (const float*)d_in[7];
    const float* W2_svv = (const float*)d_in[8];
    const float* W2_vsv = (const float*)d_in[9];
    const float* W2_vvo = (const float*)d_in[10];
    const float* W2_vvv = (const float*)d_in[11];
    float* ws = (float*)d_ws;

    fds_precompose<<<1, 256, 0, stream>>>(W1_sso, W1_svv, W1_vsv, W1_vvo, W1_vvv,
                                          W2_sso, W2_svv, W2_vsv, W2_vvo, W2_vvv, ws);

    int E = in_sizes[0] / 12;  // N*3 / 12 = N/4
    int blocks = (E + 255) / 256;
    fds_kernel<<<blocks, 256, 0, stream>>>(
        lig, rec,
        ws + WS_W12H, ws + WS_WV, ws + WS_WSH, ws + WS_CS,
        ws + WS_SVV, ws + WS_VSV, ws + WS_VVV1, ws + WS_VSV2,
        ws + WS_VVV2, ws + WS_VVO2,
        (float*)d_out, E);
}